// Round 14
// baseline (126.939 us; speedup 1.0000x reference)
//
#include <hip/hip_runtime.h>
#include <hip/hip_bf16.h>
#include <math.h>

#define HDIM 2048
#define KDIM 2048
#define SDIM 8192
#define VDIM 2048
#define BKT  64
#define NT   (KDIM / BKT)    // 32 K-tiles
#define NITER (NT / 2)       // 16 iterations x 2 K-tiles

using short8 = __attribute__((ext_vector_type(8))) short;
using f32x4  = __attribute__((ext_vector_type(4))) float;
using us8    = __attribute__((ext_vector_type(8))) unsigned short;

typedef const __attribute__((address_space(1))) void g_void;
typedef __attribute__((address_space(3))) void lds_void;

__device__ __forceinline__ unsigned short f2bf(float f) {
  union { float f; unsigned int u; } x; x.f = f;
  unsigned int r = x.u + 0x7fffu + ((x.u >> 16) & 1u);  // RNE
  return (unsigned short)(r >> 16);
}

__device__ __forceinline__ float tanh_fast(float x) {
  float e = __expf(2.0f * x);
  return 1.0f - 2.0f * __builtin_amdgcn_rcpf(e + 1.0f);
}

__device__ __forceinline__ void barrier_sync() {
  asm volatile("" ::: "memory");
  __builtin_amdgcn_s_barrier();
  asm volatile("" ::: "memory");
}

// ------- kernel A: fused f32->bf16 convert (key,Wk) + pq projection -------
__global__ __launch_bounds__(256) void cvt_pq_kernel(const float* __restrict__ key,
                                                     const float* __restrict__ Wk,
                                                     unsigned short* __restrict__ outbf,
                                                     const float* __restrict__ query,
                                                     const float* __restrict__ Wq,
                                                     float* __restrict__ pq,
                                                     int keyN8, int cvtBlocks) {
  if ((int)blockIdx.x < cvtBlocks) {
    int i = blockIdx.x * 256 + threadIdx.x;
    const float* src = (i < keyN8) ? &key[(size_t)i * 8] : &Wk[((size_t)i - keyN8) * 8];
    f32x4 a = __builtin_nontemporal_load((const f32x4*)src);
    f32x4 b = __builtin_nontemporal_load((const f32x4*)(src + 4));
    us8 o;
    #pragma unroll
    for (int j = 0; j < 4; ++j) { o[j] = f2bf(a[j]); o[j + 4] = f2bf(b[j]); }
    *(us8*)&outbf[(size_t)i * 8] = o;
  } else {
    int wave = threadIdx.x >> 6, lane = threadIdx.x & 63;
    int h = (blockIdx.x - cvtBlocks) * 4 + wave;
    const float* w = Wq + (size_t)h * KDIM;
    f32x4 s4 = (f32x4)(0.0f);
    #pragma unroll
    for (int i = 0; i < KDIM / 256; ++i) {
      f32x4 q4 = *(const f32x4*)&query[lane * 4 + i * 256];
      f32x4 w4 = __builtin_nontemporal_load((const f32x4*)&w[lane * 4 + i * 256]);
      #pragma unroll
      for (int j = 0; j < 4; ++j) s4[j] = fmaf(q4[j], w4[j], s4[j]);
    }
    float s = s4[0] + s4[1] + s4[2] + s4[3];
    #pragma unroll
    for (int off = 32; off; off >>= 1) s += __shfl_xor(s, off);
    if (lane == 0) pq[h] = s;
  }
}

// ---- kernel B: fused scores — exact m201 8-phase port ----
// 256x256 tile, 8 waves (2x4), BK=64, 2 K-tiles per iteration (dbuf0/dbuf1).
// LDS: per dbuf {A: half0 16KB | half1 16KB | B: half0 16KB | half1 16KB}.
// Halves are consumption-ordered (striped global rows remapped via per-lane
// source addressing; dest stays linear for global_load_lds).
// Per phase: reads (12/4/8/0) | stage 1 half (2 loads) | [lgkmcnt(8)] |
// barrier | lgkmcnt(0) | setprio(1) 16 MFMA setprio(0) | [vmcnt(6) @P4/P8] | barrier.
__global__ __launch_bounds__(512, 2) void scores_kernel(const unsigned short* __restrict__ keybf,
                                                        const unsigned short* __restrict__ wkbf,
                                                        const float* __restrict__ pq,
                                                        const float* __restrict__ Ws,
                                                        float* __restrict__ partial) {
  __shared__ unsigned short lds[65536];   // 128 KiB

  const int tid = threadIdx.x;
  const int bid = blockIdx.x;
  const int xg = bid & 7, xi = bid >> 3;
  const int bx = xg * 4 + (xi & 3);      // s-tile 0..31
  const int by = xi >> 2;                // h-tile 0..7
  const int s0 = bx * 256, h0 = by * 256;

  const int wave = tid >> 6, lane = tid & 63;
  const int wm = wave >> 2, wn = wave & 3;     // 2 x 4 waves; wave tile 128(s) x 64(h)
  const int l16 = lane & 15, g16 = lane >> 4;

  // ---- staging: per op, 512 threads x 16B = 64 slot-rows x 128B ----
  const int u = tid >> 3;                                  // dest slot-row 0..63
  const int scol = ((tid & 7) * 16) ^ ((u & 7) << 4);      // inverse-swizzled source col
  const int hi = u >> 5, lo = u & 31;
  const char* aP = (const char*)keybf + ((size_t)(s0 + u) * KDIM) * 2 + scol;
  const char* bP = (const char*)wkbf  + ((size_t)(h0 + hi * 64 + lo) * KDIM) * 2 + scol;

  // A half h, op o: global rows o*128 + h*64 + u ; dest A-region + h*16K + o*8K
  #define STG_A(h, o, kt, db) __builtin_amdgcn_global_load_lds( \
      (g_void*)(aP + (size_t)((o) * 128 + (h) * 64) * (KDIM * 2) + (size_t)(kt) * 128), \
      (lds_void*)((char*)lds + (db) + (h) * 16384 + (o) * 8192 + wave * 1024), 16, 0, 0)
  // B half h, op o: global rows (o*2+hi)*64 + h*32 + lo ; dest B-region + h*16K + o*8K
  #define STG_B(h, o, kt, db) __builtin_amdgcn_global_load_lds( \
      (g_void*)(bP + (size_t)((o) * 128 + (h) * 32) * (KDIM * 2) + (size_t)(kt) * 128), \
      (lds_void*)((char*)lds + (db) + 32768 + (h) * 16384 + (o) * 8192 + wave * 1024), 16, 0, 0)

  // ---- read-side ----
  const int xorv = (l16 & 7) << 4;
  int colx[2];
  colx[0] = ((g16 * 16)      ) ^ xorv;
  colx[1] = ((g16 * 16) | 64 ) ^ xorv;
  const int aOff = (64 * wm + l16) * 128;            // + m*2048 (m0-3); +16384 for m4-7
  const int bOff = 32768 + (32 * wn + l16) * 128;    // + n*2048 (n0-1); +16384 for n2-3

  #define LDA0(mm, db, ks) (*(const short8*)((const char*)lds + (db) + aOff + (mm) * 2048 + colx[ks]))
  #define LDA1(mm, db, ks) (*(const short8*)((const char*)lds + (db) + 16384 + aOff + (mm) * 2048 + colx[ks]))
  #define LDB0(nn, db, ks) (*(const short8*)((const char*)lds + (db) + bOff + (nn) * 2048 + colx[ks]))
  #define LDB1(nn, db, ks) (*(const short8*)((const char*)lds + (db) + 16384 + bOff + (nn) * 2048 + colx[ks]))

  f32x4 acc[8][4];
  #pragma unroll
  for (int m = 0; m < 8; ++m)
    #pragma unroll
    for (int n = 0; n < 4; ++n) acc[m][n] = (f32x4)(0.0f);

  // ---- prologue: tile0 full (d0), tile1 minus Ah1 (d1) ----
  STG_A(0, 0, 0, 0); STG_A(0, 1, 0, 0);          // d0.Ah0
  STG_B(0, 0, 0, 0); STG_B(0, 1, 0, 0);          // d0.Bh0
  STG_B(1, 0, 0, 0); STG_B(1, 1, 0, 0);          // d0.Bh1
  STG_A(1, 0, 0, 0); STG_A(1, 1, 0, 0);          // d0.Ah1
  STG_A(0, 0, 1, 65536); STG_A(0, 1, 1, 65536);  // d1.Ah0
  STG_B(0, 0, 1, 65536); STG_B(0, 1, 1, 65536);  // d1.Bh0
  STG_B(1, 0, 1, 65536); STG_B(1, 1, 1, 65536);  // d1.Bh1
  asm volatile("s_waitcnt vmcnt(6)" ::: "memory");  // d0 fully landed
  barrier_sync();

  short8 af[4][2], bf_[4][2];

  for (int i = 0; i < NITER; ++i) {
    const int kt0 = 2 * i, kt1 = 2 * i + 1;
    const bool more = (i + 1 < NITER);

    // ===== P1: read d0 a0-3 + b0-1 (12); stage d1.Ah1(kt1) =====
    #pragma unroll
    for (int m = 0; m < 4; ++m) { af[m][0] = LDA0(m, 0, 0); af[m][1] = LDA0(m, 0, 1); }
    #pragma unroll
    for (int n = 0; n < 2; ++n) { bf_[n][0] = LDB0(n, 0, 0); bf_[n][1] = LDB0(n, 0, 1); }
    STG_A(1, 0, kt1, 65536); STG_A(1, 1, kt1, 65536);
    asm volatile("s_waitcnt lgkmcnt(8)" ::: "memory");
    barrier_sync();
    asm volatile("s_waitcnt lgkmcnt(0)" ::: "memory");
    __builtin_amdgcn_s_setprio(1);
    #pragma unroll
    for (int ks = 0; ks < 2; ++ks)
      #pragma unroll
      for (int m = 0; m < 4; ++m)
        #pragma unroll
        for (int n = 0; n < 2; ++n)
          acc[m][n] = __builtin_amdgcn_mfma_f32_16x16x32_bf16(af[m][ks], bf_[n][ks], acc[m][n], 0, 0, 0);
    __builtin_amdgcn_s_setprio(0);
    barrier_sync();

    // ===== P2: read d0 b2-3 (4); stage d0.Ah0(kt0+2) =====
    #pragma unroll
    for (int n = 2; n < 4; ++n) { bf_[n][0] = LDB1(n - 2, 0, 0); bf_[n][1] = LDB1(n - 2, 0, 1); }
    if (more) { STG_A(0, 0, kt0 + 2, 0); STG_A(0, 1, kt0 + 2, 0); }
    barrier_sync();
    asm volatile("s_waitcnt lgkmcnt(0)" ::: "memory");
    __builtin_amdgcn_s_setprio(1);
    #pragma unroll
    for (int ks = 0; ks < 2; ++ks)
      #pragma unroll
      for (int m = 0; m < 4; ++m)
        #pragma unroll
        for (int n = 2; n < 4; ++n)
          acc[m][n] = __builtin_amdgcn_mfma_f32_16x16x32_bf16(af[m][ks], bf_[n][ks], acc[m][n], 0, 0, 0);
    __builtin_amdgcn_s_setprio(0);
    barrier_sync();

    // ===== P3: read d0 a4-7 (8); stage d0.Bh0(kt0+2) =====
    #pragma unroll
    for (int m = 0; m < 4; ++m) { af[m][0] = LDA1(m, 0, 0); af[m][1] = LDA1(m, 0, 1); }
    if (more) { STG_B(0, 0, kt0 + 2, 0); STG_B(0, 1, kt0 + 2, 0); }
    barrier_sync();
    asm volatile("s_waitcnt lgkmcnt(0)" ::: "memory");
    __builtin_amdgcn_s_setprio(1);
    #pragma unroll
    for (int ks = 0; ks < 2; ++ks)
      #pragma unroll
      for (int m = 0; m < 4; ++m)
        #pragma unroll
        for (int n = 2; n < 4; ++n)
          acc[m + 4][n] = __builtin_amdgcn_mfma_f32_16x16x32_bf16(af[m][ks], bf_[n][ks], acc[m + 4][n], 0, 0, 0);
    __builtin_amdgcn_s_setprio(0);
    barrier_sync();

    // ===== P4: stage d0.Bh1(kt0+2); MFMA m4-7 x n0-1; vmcnt =====
    if (more) { STG_B(1, 0, kt0 + 2, 0); STG_B(1, 1, kt0 + 2, 0); }
    barrier_sync();
    __builtin_amdgcn_s_setprio(1);
    #pragma unroll
    for (int ks = 0; ks < 2; ++ks)
      #pragma unroll
      for (int m = 0; m < 4; ++m)
        #pragma unroll
        for (int n = 0; n < 2; ++n)
          acc[m + 4][n] = __builtin_amdgcn_mfma_f32_16x16x32_bf16(af[m][ks], bf_[n][ks], acc[m + 4][n], 0, 0, 0);
    __builtin_amdgcn_s_setprio(0);
    if (more) asm volatile("s_waitcnt vmcnt(6)" ::: "memory");
    else      asm volatile("s_waitcnt vmcnt(0)" ::: "memory");
    barrier_sync();

    // ===== P5: read d1 a0-3 + b0-1 (12); stage d0.Ah1(kt0+2) =====
    #pragma unroll
    for (int m = 0; m < 4; ++m) { af[m][0] = LDA0(m, 65536, 0); af[m][1] = LDA0(m, 65536, 1); }
    #pragma unroll
    for (int n = 0; n < 2; ++n) { bf_[n][0] = LDB0(n, 65536, 0); bf_[n][1] = LDB0(n, 65536, 1); }
    if (more) { STG_A(1, 0, kt0 + 2, 0); STG_A(1, 1, kt0 + 2, 0); }
    asm volatile("s_waitcnt lgkmcnt(8)" ::: "memory");
    barrier_sync();
    asm volatile("s_waitcnt lgkmcnt(0)" ::: "memory");
    __builtin_amdgcn_s_setprio(1);
    #pragma unroll
    for (int ks = 0; ks < 2; ++ks)
      #pragma unroll
      for (int m = 0; m < 4; ++m)
        #pragma unroll
        for (int n = 0; n < 2; ++n)
          acc[m][n] = __builtin_amdgcn_mfma_f32_16x16x32_bf16(af[m][ks], bf_[n][ks], acc[m][n], 0, 0, 0);
    __builtin_amdgcn_s_setprio(0);
    barrier_sync();

    // ===== P6: read d1 b2-3 (4); stage d1.Ah0(kt1+2) =====
    #pragma unroll
    for (int n = 2; n < 4; ++n) { bf_[n][0] = LDB1(n - 2, 65536, 0); bf_[n][1] = LDB1(n - 2, 65536, 1); }
    if (more) { STG_A(0, 0, kt1 + 2, 65536); STG_A(0, 1, kt1 + 2, 65536); }
    barrier_sync();
    asm volatile("s_waitcnt lgkmcnt(0)" ::: "memory");
    __builtin_amdgcn_s_setprio(1);
    #pragma unroll
    for (int ks = 0; ks < 2; ++ks)
      #pragma unroll
      for (int m = 0; m < 4; ++m)
        #pragma unroll
        for (int n = 2; n < 4; ++n)
          acc[m][n] = __builtin_amdgcn_mfma_f32_16x16x32_bf16(af[m][ks], bf_[n][ks], acc[m][n], 0, 0, 0);
    __builtin_amdgcn_s_setprio(0);
    barrier_sync();

    // ===== P7: read d1 a4-7 (8); stage d1.Bh0(kt1+2) =====
    #pragma unroll
    for (int m = 0; m < 4; ++m) { af[m][0] = LDA1(m, 65536, 0); af[m][1] = LDA1(m, 65536, 1); }
    if (more) { STG_B(0, 0, kt1 + 2, 65536); STG_B(0, 1, kt1 + 2, 65536); }
    barrier_sync();
    asm volatile("s_waitcnt lgkmcnt(0)" ::: "memory");
    __builtin_amdgcn_s_setprio(1);
    #pragma unroll
    for (int ks = 0; ks < 2; ++ks)
      #pragma unroll
      for (int m = 0; m < 4; ++m)
        #pragma unroll
        for (int n = 2; n < 4; ++n)
          acc[m + 4][n] = __builtin_amdgcn_mfma_f32_16x16x32_bf16(af[m][ks], bf_[n][ks], acc[m + 4][n], 0, 0, 0);
    __builtin_amdgcn_s_setprio(0);
    barrier_sync();

    // ===== P8: stage d1.Bh1(kt1+2); MFMA m4-7 x n0-1; vmcnt =====
    if (more) { STG_B(1, 0, kt1 + 2, 65536); STG_B(1, 1, kt1 + 2, 65536); }
    barrier_sync();
    __builtin_amdgcn_s_setprio(1);
    #pragma unroll
    for (int ks = 0; ks < 2; ++ks)
      #pragma unroll
      for (int m = 0; m < 4; ++m)
        #pragma unroll
        for (int n = 0; n < 2; ++n)
          acc[m + 4][n] = __builtin_amdgcn_mfma_f32_16x16x32_bf16(af[m][ks], bf_[n][ks], acc[m + 4][n], 0, 0, 0);
    __builtin_amdgcn_s_setprio(0);
    if (more) asm volatile("s_waitcnt vmcnt(6)" ::: "memory");
    else      asm volatile("s_waitcnt vmcnt(0)" ::: "memory");
    barrier_sync();
  }

  // ---- epilogue: h = h0 + wn*64 + n*16 + l16 ; s = s0 + wm*128 + m*16 + g16*4 + j
  float pqv[4], wsv[4];
  #pragma unroll
  for (int n = 0; n < 4; ++n) {
    int h = h0 + wn * 64 + n * 16 + l16;
    pqv[n] = pq[h];
    wsv[n] = Ws[h];
  }

  float* sred = (float*)lds;   // [256][4] overlay
  #pragma unroll
  for (int m = 0; m < 8; ++m) {
    #pragma unroll
    for (int j = 0; j < 4; ++j) {
      float rs = 0.f;
      #pragma unroll
      for (int n = 0; n < 4; ++n)
        rs += tanh_fast(acc[m][n][j] + pqv[n]) * wsv[n];
      rs += __shfl_xor(rs, 1);
      rs += __shfl_xor(rs, 2);
      rs += __shfl_xor(rs, 4);
      rs += __shfl_xor(rs, 8);
      if (l16 == 0)
        sred[(wm * 128 + m * 16 + g16 * 4 + j) * 4 + wn] = rs;
    }
  }
  __syncthreads();
  if (tid < 256) {
    float v = sred[tid * 4 + 0] + sred[tid * 4 + 1] + sred[tid * 4 + 2] + sred[tid * 4 + 3];
    partial[(size_t)(s0 + tid) * 8 + by] = v;
  }
}

// ---- kernel C: per-chunk softmax partials. 32 blocks x 256 s-rows ----
__global__ __launch_bounds__(256) void smax_part_kernel(const float* __restrict__ partial,
                                                        float* __restrict__ wexp,
                                                        float* __restrict__ pairs) {
  __shared__ float red[8];
  int tid = threadIdx.x, wave = tid >> 6, lane = tid & 63;
  int s = blockIdx.x * 256 + tid;
  const float* p = partial + (size_t)s * 8;
  float v = 0.f;
  #pragma unroll
  for (int q = 0; q < 8; ++q) v += p[q];
  float mx = v;
  #pragma unroll
  for (int off = 32; off; off >>= 1) mx = fmaxf(mx, __shfl_xor(mx, off));
  if (lane == 0) red[wave] = mx;
  __syncthreads();
  float bmax = fmaxf(fmaxf(red[0], red[1]), fmaxf(red[2], red[3]));
  float e = __expf(v - bmax);
  wexp[s] = e;
  float sm = e;
  #pragma unroll
  for (int off = 32; off; off >>= 1) sm += __shfl_xor(sm, off);
  if (lane == 0) red[4 + wave] = sm;
  __syncthreads();
  if (tid == 0)
    { pairs[blockIdx.x * 2] = bmax; pairs[blockIdx.x * 2 + 1] = red[4] + red[5] + red[6] + red[7]; }
}

// ---- kernel D: fused global-softmax finish + weights write + context ----
__global__ __launch_bounds__(256) void ctx_fused_kernel(const float* __restrict__ values,
                                                        const float* __restrict__ wexp,
                                                        const float* __restrict__ pairs,
                                                        float* __restrict__ weights,
                                                        float* __restrict__ ctx) {
  __shared__ float scl[32];
  __shared__ f32x4 sred[256];
  int tid = threadIdx.x, b = blockIdx.x;

  float gmax = -1e30f;
  #pragma unroll
  for (int i = 0; i < 32; ++i) gmax = fmaxf(gmax, pairs[2 * i]);
  float gs = 0.f;
  #pragma unroll
  for (int i = 0; i < 32; ++i) gs += pairs[2 * i + 1] * __expf(pairs[2 * i] - gmax);
  if (tid < 32) scl[tid] = __expf(pairs[2 * tid] - gmax);
  __syncthreads();
  float inv = 1.0f / gs;

  if (b < 32) {
    int s = b * 256 + tid;
    weights[s] = wexp[s] * scl[b] * inv;
  }

  const int c4 = b * 2 + (tid & 1);    // float4 column index (8 cols per block)
  const int g  = tid >> 1;             // 128 s-groups
  f32x4 acc = (f32x4)(0.0f);
  for (int s = g; s < SDIM; s += 128) {
    float w = wexp[s] * scl[s >> 8];
    f32x4 v = *(const f32x4*)&values[(size_t)s * VDIM + c4 * 4];
    #pragma unroll
    for (int j = 0; j < 4; ++j) acc[j] = fmaf(w, v[j], acc[j]);
  }
  sred[tid] = acc;
  #pragma unroll
  for (int step = 64; step; step >>= 1) {
    __syncthreads();
    if (g < step) {
      f32x4 a = sred[tid], o = sred[tid + step * 2];
      #pragma unroll
      for (int j = 0; j < 4; ++j) a[j] += o[j];
      sred[tid] = a;
    }
  }
  __syncthreads();
  if (tid < 2) {
    f32x4 a = sred[tid];
    #pragma unroll
    for (int j = 0; j < 4; ++j) a[j] *= inv;
    *(f32x4*)&ctx[(size_t)(b * 2 + tid) * 4] = a;
  }
}

extern "C" void kernel_launch(void* const* d_in, const int* in_sizes, int n_in,
                              void* d_out, int out_size, void* d_ws, size_t ws_size,
                              hipStream_t stream) {
  const float* query  = (const float*)d_in[0];
  const float* key    = (const float*)d_in[1];
  const float* values = (const float*)d_in[2];
  const float* Wq     = (const float*)d_in[3];
  const float* Wk     = (const float*)d_in[4];
  const float* Ws     = (const float*)d_in[5];

  float* out     = (float*)d_out;
  float* weights = out;          // [8192]
  float* ctx     = out + SDIM;   // [2048]

  char* ws = (char*)d_ws;
  unsigned short* keybf = (unsigned short*)ws;                              // 32 MiB
  unsigned short* wkbf  = (unsigned short*)(ws + (size_t)SDIM * KDIM * 2);  // 8 MiB
  char* tail = ws + (size_t)SDIM * KDIM * 2 + (size_t)HDIM * KDIM * 2;
  float* pq      = (float*)tail;                           // 2048 f32
  float* partial = (float*)(tail + 8192);                  // 8192*8 f32 (256 KiB)
  float* wexp    = (float*)(tail + 8192 + (size_t)SDIM * 8 * 4);   // 8192 f32
  float* pairs   = wexp + SDIM;                            // 64 f32

  const int keyN8 = SDIM * KDIM / 8;
  const int totN8 = keyN8 + HDIM * KDIM / 8;
  const int cvtBlocks = totN8 / 256;   // 10240 (exact)
  cvt_pq_kernel<<<cvtBlocks + HDIM / 4, 256, 0, stream>>>(key, Wk, keybf, query, Wq, pq,
                                                          keyN8, cvtBlocks);
  scores_kernel<<<256, 512, 0, stream>>>(keybf, wkbf, pq, Ws, partial);
  smax_part_kernel<<<32, 256, 0, stream>>>(partial, wexp, pairs);
  ctx_fused_kernel<<<256, 256, 0, stream>>>(values, wexp, pairs, weights, ctx);
}